// Round 4
// baseline (562.958 us; speedup 1.0000x reference)
//
#include <hip/hip_runtime.h>

// RGCN 2-layer: N=50000, E=800000, R=8, 64->64->32, fp32.
// R4: fused gather+GEMM (aggregate-then-transform, no materialized A).
//   memset(seg) -> hist -> 3-phase scan -> scatter (CSR by (dst,rel)) ->
//   fused1: buf1 = [mean-agg(x) per rel | x] @ vstack(W1,root1) + b1
//   fused2: out  = [mean-agg(relu(buf1)) | relu(buf1)] @ vstack(W2,root2) + b2
// Fused kernel: 64-node tile, 9 K-phases (8 rels + root); A-tile gathered
// straight into LDS As[k][m] (pad 66); W tile in Bs; 256 thr, 4x(TN/16) micro.
// ws ~18MB.

#define NN 50000
#define NE 800000
#define NR 8
#define NPR (NN * NR)              // 400000 segments
#define NBLK ((NPR + 1023) / 1024) // 391 scan blocks

// ---- per-(dst,rel) incoming-edge count into seg[] ---------------------------
__global__ __launch_bounds__(256) void k_hist(const int* __restrict__ dst,
                                              const int* __restrict__ et,
                                              int* __restrict__ seg) {
  int e = blockIdx.x * 256 + threadIdx.x;
  if (e < NE) atomicAdd(&seg[dst[e] * NR + et[e]], 1);
}

// ---- 3-phase exclusive scan of seg[NPR] (in place) --------------------------
__global__ __launch_bounds__(256) void k_scanA(const int* __restrict__ seg,
                                               int* __restrict__ bsum) {
  __shared__ int red[256];
  const int t = threadIdx.x;
  const int base = blockIdx.x * 1024 + t * 4;
  int s = 0;
#pragma unroll
  for (int j = 0; j < 4; ++j)
    if (base + j < NPR) s += seg[base + j];
  red[t] = s;
  __syncthreads();
  for (int off = 128; off > 0; off >>= 1) {
    if (t < off) red[t] += red[t + off];
    __syncthreads();
  }
  if (t == 0) bsum[blockIdx.x] = red[0];
}

__global__ __launch_bounds__(512) void k_scanB(const int* __restrict__ bsum,
                                               int* __restrict__ boff) {
  __shared__ int ps[512];
  const int t = threadIdx.x;
  const int v = (t < NBLK) ? bsum[t] : 0;
  ps[t] = v;
  __syncthreads();
  for (int off = 1; off < 512; off <<= 1) {
    int u = (t >= off) ? ps[t - off] : 0;
    __syncthreads();
    ps[t] += u;
    __syncthreads();
  }
  if (t < NBLK) boff[t] = ps[t] - v;  // exclusive
}

__global__ __launch_bounds__(256) void k_scanC(int* __restrict__ seg,
                                               const int* __restrict__ boff) {
  __shared__ int ps[256];
  const int t = threadIdx.x;
  const int base = blockIdx.x * 1024 + t * 4;
  int v[4];
  int s = 0;
#pragma unroll
  for (int j = 0; j < 4; ++j) {
    v[j] = (base + j < NPR) ? seg[base + j] : 0;
    s += v[j];
  }
  ps[t] = s;
  __syncthreads();
  for (int off = 1; off < 256; off <<= 1) {
    int u = (t >= off) ? ps[t - off] : 0;
    __syncthreads();
    ps[t] += u;
    __syncthreads();
  }
  int run = ps[t] - s + boff[blockIdx.x];
#pragma unroll
  for (int j = 0; j < 4; ++j) {
    if (base + j < NPR) {
      int old = v[j];
      seg[base + j] = run;  // exclusive prefix
      run += old;
    }
  }
}

// ---- scatter: perm sorted by (dst,rel); seg becomes inclusive segment ends --
__global__ __launch_bounds__(256) void k_scatter(const int* __restrict__ src,
                                                 const int* __restrict__ dst,
                                                 const int* __restrict__ et,
                                                 int* __restrict__ seg,
                                                 int* __restrict__ perm) {
  int e = blockIdx.x * 256 + threadIdx.x;
  if (e < NE) {
    int pos = atomicAdd(&seg[dst[e] * NR + et[e]], 1);
    perm[pos] = src[e];
  }
}

// ---- fused gather+GEMM ------------------------------------------------------
// C[64-node tile, TN] = sum_{r} meanagg_r(feat) @ W[r] + feat @ root + bias
// As[k][m] pad 66: gather-write bank-cheap, compute-read (float2 pairs,
// broadcast) conflict-free. Bs[k][n] staged per phase.
template <int TN, bool RELU>
__global__ __launch_bounds__(256) void k_fused(const float* __restrict__ feat,
                                               const int* __restrict__ perm,
                                               const int* __restrict__ seg,
                                               const float* __restrict__ W,
                                               const float* __restrict__ root,
                                               const float* __restrict__ bias,
                                               float* __restrict__ C) {
  __shared__ float As[64][66];
  __shared__ float Bs[64][TN];
  const int tid  = threadIdx.x;
  const int n0   = blockIdx.x * 64;
  const int lane = tid & 63;
  const int wv   = tid >> 6;        // wave 0..3: nodes wv*16..wv*16+15
  const int ty   = tid >> 4;        // 0..15: m-group of 4 rows
  const int tx   = tid & 15;        // 0..15: n-group of JW cols
  constexpr int JW = TN / 16;       // 4 (TN=64) | 2 (TN=32)
  float acc[4][JW];
#pragma unroll
  for (int i = 0; i < 4; ++i)
#pragma unroll
    for (int j = 0; j < JW; ++j) acc[i][j] = 0.f;

  for (int kt = 0; kt < 9; ++kt) {
    // ---- stage A-tile: gather rel kt (or root rows) into As[k=feat][m=node]
    for (int i = 0; i < 16; ++i) {
      const int nl = wv * 16 + i;
      const int n  = n0 + nl;
      float val = 0.f;
      if (n < NN) {
        if (kt < 8) {
          const int idx = n * NR + kt;
          const int s0 = (idx == 0) ? 0 : seg[idx - 1];
          const int e0 = seg[idx];
          float a0 = 0.f, a1 = 0.f;
          int e = s0;
          for (; e + 1 < e0; e += 2) {
            float v0 = feat[(size_t)perm[e] * 64 + lane];
            float v1 = feat[(size_t)perm[e + 1] * 64 + lane];
            if (RELU) { v0 = fmaxf(v0, 0.f); v1 = fmaxf(v1, 0.f); }
            a0 += v0;
            a1 += v1;
          }
          if (e < e0) {
            float v = feat[(size_t)perm[e] * 64 + lane];
            if (RELU) v = fmaxf(v, 0.f);
            a0 += v;
          }
          const int c = e0 - s0;
          val = (a0 + a1) * (1.0f / (float)(c < 1 ? 1 : c));
        } else {
          float v = feat[(size_t)n * 64 + lane];
          if (RELU) v = fmaxf(v, 0.f);
          val = v;
        }
      }
      As[lane][nl] = val;
    }
    // ---- stage B-tile: W[kt] (64 x TN) or root ----
    {
      const float* __restrict__ Bsrc = (kt < 8) ? (W + (size_t)kt * 64 * TN) : root;
      if (TN == 64) {
        const int kr = tid >> 4, lf = tid & 15;
#pragma unroll
        for (int pass = 0; pass < 4; ++pass) {
          const int k = kr + pass * 16;
          *(float4*)&Bs[k][lf * 4] = *(const float4*)&Bsrc[k * TN + lf * 4];
        }
      } else {
        const int kr = tid >> 3, lf = tid & 7;
#pragma unroll
        for (int pass = 0; pass < 2; ++pass) {
          const int k = kr + pass * 32;
          *(float4*)&Bs[k][lf * 4] = *(const float4*)&Bsrc[k * TN + lf * 4];
        }
      }
    }
    __syncthreads();
    // ---- compute: 4m x JW n per thread ----
#pragma unroll 4
    for (int k = 0; k < 64; ++k) {
      float a[4], b[JW];
      *(float2*)&a[0] = *(const float2*)&As[k][ty * 4];
      *(float2*)&a[2] = *(const float2*)&As[k][ty * 4 + 2];
      if (TN == 64) {
        *(float4*)&b[0] = *(const float4*)&Bs[k][tx * 4];
      } else {
        *(float2*)&b[0] = *(const float2*)&Bs[k][tx * 2];
      }
#pragma unroll
      for (int i = 0; i < 4; ++i)
#pragma unroll
        for (int j = 0; j < JW; ++j) acc[i][j] = fmaf(a[i], b[j], acc[i][j]);
    }
    __syncthreads();
  }
  // ---- epilogue: + bias, store ----
  float bv[JW];
#pragma unroll
  for (int j = 0; j < JW; ++j) bv[j] = bias[tx * JW + j];
#pragma unroll
  for (int i = 0; i < 4; ++i) {
    const int n = n0 + ty * 4 + i;
    if (n < NN) {
#pragma unroll
      for (int j = 0; j < JW; ++j) acc[i][j] += bv[j];
      if (TN == 64) {
        *(float4*)&C[(size_t)n * 64 + tx * 4] = *(float4*)&acc[i][0];
      } else {
        *(float2*)&C[(size_t)n * 32 + tx * 2] = *(float2*)&acc[i][0];
      }
    }
  }
}

// =============================================================================
extern "C" void kernel_launch(void* const* d_in, const int* in_sizes, int n_in,
                              void* d_out, int out_size, void* d_ws, size_t ws_size,
                              hipStream_t stream) {
  const float* x     = (const float*)d_in[0];
  const int*   ei    = (const int*)d_in[1];
  const int*   et    = (const int*)d_in[2];
  const float* W1    = (const float*)d_in[3];
  const float* root1 = (const float*)d_in[4];
  const float* b1    = (const float*)d_in[5];
  const float* W2    = (const float*)d_in[6];
  const float* root2 = (const float*)d_in[7];
  const float* b2    = (const float*)d_in[8];
  float* out = (float*)d_out;
  const int* srcA = ei;
  const int* dstA = ei + NE;

  // ws layout (~18MB)
  char* w = (char*)d_ws;
  size_t off = 0;
  int* seg  = (int*)(w + off); off += (size_t)NPR * 4;        // 1.6MB
  int* bsum = (int*)(w + off); off += (size_t)NBLK * 4;
  int* boff = (int*)(w + off); off += (size_t)NBLK * 4;
  int* perm = (int*)(w + off); off += (size_t)NE * 4;         // 3.2MB
  off = (off + 15) & ~(size_t)15;
  float* buf1 = (float*)(w + off); off += (size_t)NN * 64 * 4;   // 12.8MB

  hipMemsetAsync(seg, 0, (size_t)NPR * 4, stream);
  k_hist<<<(NE + 255) / 256, 256, 0, stream>>>(dstA, et, seg);
  k_scanA<<<NBLK, 256, 0, stream>>>(seg, bsum);
  k_scanB<<<1, 512, 0, stream>>>(bsum, boff);
  k_scanC<<<NBLK, 256, 0, stream>>>(seg, boff);
  k_scatter<<<(NE + 255) / 256, 256, 0, stream>>>(srcA, dstA, et, seg, perm);

  const int NB = (NN + 63) / 64;  // 782
  k_fused<64, false><<<NB, 256, 0, stream>>>(x, perm, seg, W1, root1, b1, buf1);
  k_fused<32, true ><<<NB, 256, 0, stream>>>(buf1, perm, seg, W2, root2, b2, out);
}